// Round 7
// baseline (346.561 us; speedup 1.0000x reference)
//
#include <hip/hip_runtime.h>
#include <math.h>

#define EPSF 1e-7f
#define YMAXF 0.99999f   // fp32(1 - 1e-5), same rounding as jnp clip constant
#define WPITCH 136       // bf16 pitch: 272 B/row -> <=2-way bank alias (free)

#define NBUCK 256        // dst buckets: bucket = dst >> 9 (needs N <= 131072)
#define PB_CHUNK 2048    // edges per bucket_scatter block

typedef short bf16x8 __attribute__((ext_vector_type(8)));
typedef short bf16x4 __attribute__((ext_vector_type(4)));
typedef short bf16x2 __attribute__((ext_vector_type(2)));
typedef float f32x4  __attribute__((ext_vector_type(4)));

__device__ __forceinline__ float grp32_sum(float v) {
    v += __shfl_xor(v, 1);
    v += __shfl_xor(v, 2);
    v += __shfl_xor(v, 4);
    v += __shfl_xor(v, 8);
    v += __shfl_xor(v, 16);
    return v;
}

__device__ __forceinline__ short f2bf(float f) {
    unsigned u = __float_as_uint(f);
    unsigned r = (u + 0x7FFFu + ((u >> 16) & 1u)) >> 16;
    return (short)r;
}

__device__ __forceinline__ float bf2f(short u) {
    return __uint_as_float(((unsigned)(unsigned short)u) << 16);
}

// Kernel 1: v = log_map_zero(x), stored bf16
__global__ void logmap_kernel(const float* __restrict__ x,
                              const float* __restrict__ c_ptr,
                              short* __restrict__ v_bf,
                              int N) {
    int gid = blockIdx.x * blockDim.x + threadIdx.x;
    int row = gid >> 5;
    if (row >= N) return;
    int lane = gid & 31;
    const float4 xv = ((const float4*)x)[(size_t)row * 32 + lane];
    float ss = xv.x * xv.x + xv.y * xv.y + xv.z * xv.z + xv.w * xv.w;
    ss = grp32_sum(ss);
    float sc = sqrtf(c_ptr[0]);
    float xn = fmaxf(sqrtf(ss), EPSF);
    float y = fminf(sc * xn, YMAXF);
    float s = atanhf(y) / (sc * xn);
    bf16x4 pk;
    pk[0] = f2bf(s * xv.x); pk[1] = f2bf(s * xv.y);
    pk[2] = f2bf(s * xv.z); pk[3] = f2bf(s * xv.w);
    *(bf16x4*)&v_bf[(size_t)row * 128 + lane * 4] = pk;
}

// Pass A: count edges per coarse bucket (bucket = dst>>9)
__global__ __launch_bounds__(256)
void bucket_count_kernel(const int* __restrict__ eidx_dst,
                         int* __restrict__ bucketCount, int E) {
    __shared__ int h[NBUCK];
    int tid = threadIdx.x;
    h[tid] = 0;
    __syncthreads();
    int per = (E + gridDim.x - 1) / gridDim.x;
    int start = blockIdx.x * per;
    int end = min(start + per, E);
    for (int i = start + tid; i < end; i += 256)
        atomicAdd(&h[eidx_dst[i] >> 9], 1);
    __syncthreads();
    if (h[tid]) atomicAdd(&bucketCount[tid], h[tid]);
}

// Pass B: partition edges into coarse buckets. In-block scan of the global
// bucketCount replaces the separate scan kernel; cursor[] starts at 0 and
// positions are bucket_base + reserved offset.
__global__ __launch_bounds__(256)
void bucket_scatter_kernel(const int* __restrict__ eidx,
                           const int* __restrict__ bucketCount,
                           int* __restrict__ cursor,
                           int* __restrict__ bucketed, int E) {
    __shared__ int hist[NBUCK];
    __shared__ int lstart[NBUCK];
    __shared__ int gbase[NBUCK];
    __shared__ int part[256];
    __shared__ int stage[PB_CHUNK];
    __shared__ unsigned char stageB[PB_CHUNK];

    int tid = threadIdx.x;
    int start = blockIdx.x * PB_CHUNK;
    int cnt = min(PB_CHUNK, E - start);
    hist[tid] = 0;
    __syncthreads();

    const int J = PB_CHUNK / 256;
    int myP[J], myB[J], myR[J];
    #pragma unroll
    for (int j = 0; j < J; ++j) {
        int idx = j * 256 + tid;
        myR[j] = -1;
        if (idx < cnt) {
            int e = start + idx;
            int d = eidx[E + e];
            int s = eidx[e];
            int b = d >> 9;
            myB[j] = b;
            myP[j] = ((d & 511) << 17) | s;
            myR[j] = atomicAdd(&hist[b], 1);
        }
    }
    __syncthreads();
    // scan local hist -> lstart
    part[tid] = hist[tid];
    __syncthreads();
    for (int off = 1; off < 256; off <<= 1) {
        int t = (tid >= off) ? part[tid - off] : 0;
        __syncthreads();
        part[tid] += t;
        __syncthreads();
    }
    lstart[tid] = part[tid] - hist[tid];
    __syncthreads();
    // scan global bucketCount -> bucket base, reserve global positions
    int bc = bucketCount[tid];
    part[tid] = bc;
    __syncthreads();
    for (int off = 1; off < 256; off <<= 1) {
        int t = (tid >= off) ? part[tid - off] : 0;
        __syncthreads();
        part[tid] += t;
        __syncthreads();
    }
    int base = part[tid] - bc;
    if (hist[tid]) gbase[tid] = base + atomicAdd(&cursor[tid], hist[tid]);
    __syncthreads();
    #pragma unroll
    for (int j = 0; j < J; ++j) {
        if (myR[j] >= 0) {
            int pos = lstart[myB[j]] + myR[j];
            stage[pos] = myP[j];
            stageB[pos] = (unsigned char)myB[j];
        }
    }
    __syncthreads();
    for (int i = tid; i < cnt; i += 256) {
        int b = stageB[i];
        bucketed[gbase[b] + (i - lstart[b])] = stage[i];
    }
}

// Pass C: per-bucket fine partition -> CSR (offsets = segment start, deg).
// Bucket base recomputed by in-block scan of bucketCount.
__global__ __launch_bounds__(256)
void csr_kernel(const int* __restrict__ bucketed,
                const int* __restrict__ bucketCount,
                int* __restrict__ offsets, int* __restrict__ deg,
                int* __restrict__ sorted_src, int N) {
    __shared__ int hist[512];
    __shared__ int pre[512];
    __shared__ int cur[512];
    __shared__ int part[256];
    __shared__ int startEnd[2];
    int b = blockIdx.x;
    int tid = threadIdx.x;
    // in-block scan of bucketCount for this bucket's [start,end)
    int bc = bucketCount[tid];
    part[tid] = bc;
    __syncthreads();
    for (int off = 1; off < 256; off <<= 1) {
        int t = (tid >= off) ? part[tid - off] : 0;
        __syncthreads();
        part[tid] += t;
        __syncthreads();
    }
    if (tid == b) { startEnd[0] = part[tid] - bc; startEnd[1] = part[tid]; }
    hist[tid] = 0;
    hist[tid + 256] = 0;
    __syncthreads();
    int start = startEnd[0];
    int end = startEnd[1];
    for (int i = start + tid; i < end; i += 256)
        atomicAdd(&hist[bucketed[i] >> 17], 1);
    __syncthreads();
    int a0 = hist[2 * tid], a1 = hist[2 * tid + 1];
    part[tid] = a0 + a1;
    __syncthreads();
    for (int off = 1; off < 256; off <<= 1) {
        int t = (tid >= off) ? part[tid - off] : 0;
        __syncthreads();
        part[tid] += t;
        __syncthreads();
    }
    int base2 = part[tid] - (a0 + a1);
    pre[2 * tid] = base2;
    pre[2 * tid + 1] = base2 + a0;
    cur[2 * tid] = base2;
    cur[2 * tid + 1] = base2 + a0;
    __syncthreads();
    int node0 = b << 9;
    for (int i = tid; i < 512; i += 256) {
        int node = node0 + i;
        if (node < N) { offsets[node] = start + pre[i]; deg[node] = hist[i]; }
    }
    for (int i = start + tid; i < end; i += 256) {
        int p = bucketed[i];
        int ld = p >> 17;
        int src = p & 0x1FFFF;
        int r = atomicAdd(&cur[ld], 1);
        sorted_src[start + r] = src;
    }
}

// Gather: ONE 64-lane wave per dst row (no intra-wave divergence). bf16x2/lane
// row reads; 4-way unrolled independent loads; fp32 accum; computes the
// exp/log-map scale in-wave and writes v2 directly as bf16.
__global__ __launch_bounds__(256)
void gather_kernel(const short* __restrict__ v_bf,
                   const int* __restrict__ sorted_src,
                   const int* __restrict__ offsets,
                   const int* __restrict__ deg,
                   const float* __restrict__ c_ptr,
                   short* __restrict__ v2_bf,
                   int N) {
    int row = (blockIdx.x * 256 + threadIdx.x) >> 6;
    if (row >= N) return;
    int lane = threadIdx.x & 63;
    int start = offsets[row];
    int d = deg[row];

    bf16x2 sf = *(const bf16x2*)&v_bf[(size_t)row * 128 + lane * 2];
    float a0 = bf2f(sf[0]);
    float a1 = bf2f(sf[1]);

    int j = 0;
    for (; j + 64 <= d; j += 64) {
        int batch = sorted_src[start + j + lane];
        #pragma unroll
        for (int jj = 0; jj < 64; jj += 4) {
            int i0 = __shfl(batch, jj);
            int i1 = __shfl(batch, jj + 1);
            int i2 = __shfl(batch, jj + 2);
            int i3 = __shfl(batch, jj + 3);
            bf16x2 r0 = *(const bf16x2*)&v_bf[(size_t)i0 * 128 + lane * 2];
            bf16x2 r1 = *(const bf16x2*)&v_bf[(size_t)i1 * 128 + lane * 2];
            bf16x2 r2 = *(const bf16x2*)&v_bf[(size_t)i2 * 128 + lane * 2];
            bf16x2 r3 = *(const bf16x2*)&v_bf[(size_t)i3 * 128 + lane * 2];
            a0 += (bf2f(r0[0]) + bf2f(r1[0])) + (bf2f(r2[0]) + bf2f(r3[0]));
            a1 += (bf2f(r0[1]) + bf2f(r1[1])) + (bf2f(r2[1]) + bf2f(r3[1]));
        }
    }
    int m = d - j;
    if (m > 0) {
        int batch = (lane < m) ? sorted_src[start + j + lane] : 0;
        int jj = 0;
        for (; jj + 4 <= m; jj += 4) {
            int i0 = __shfl(batch, jj);
            int i1 = __shfl(batch, jj + 1);
            int i2 = __shfl(batch, jj + 2);
            int i3 = __shfl(batch, jj + 3);
            bf16x2 r0 = *(const bf16x2*)&v_bf[(size_t)i0 * 128 + lane * 2];
            bf16x2 r1 = *(const bf16x2*)&v_bf[(size_t)i1 * 128 + lane * 2];
            bf16x2 r2 = *(const bf16x2*)&v_bf[(size_t)i2 * 128 + lane * 2];
            bf16x2 r3 = *(const bf16x2*)&v_bf[(size_t)i3 * 128 + lane * 2];
            a0 += (bf2f(r0[0]) + bf2f(r1[0])) + (bf2f(r2[0]) + bf2f(r3[0]));
            a1 += (bf2f(r0[1]) + bf2f(r1[1])) + (bf2f(r2[1]) + bf2f(r3[1]));
        }
        for (; jj < m; ++jj) {
            int s = __shfl(batch, jj);
            bf16x2 r = *(const bf16x2*)&v_bf[(size_t)s * 128 + lane * 2];
            a0 += bf2f(r[0]);
            a1 += bf2f(r[1]);
        }
    }
    float inv = 1.0f / (float)(d + 1);
    a0 *= inv;
    a1 *= inv;

    float ss = a0 * a0 + a1 * a1;
    ss += __shfl_xor(ss, 1);
    ss += __shfl_xor(ss, 2);
    ss += __shfl_xor(ss, 4);
    ss += __shfl_xor(ss, 8);
    ss += __shfl_xor(ss, 16);
    ss += __shfl_xor(ss, 32);

    float sc  = sqrtf(c_ptr[0]);
    float vn  = sqrtf(ss);
    float vnc = fmaxf(vn, EPSF);
    float th  = tanhf(sc * vnc);
    float tt  = th / (sc * vnc);          // x_hyp = tt * v_agg
    float hn  = fmaxf(th / sc, EPSF);
    float y2  = fminf(sc * hn, YMAXF);
    float s2  = atanhf(y2) / (sc * hn);   // v2 = s2 * x_hyp
    float scale = s2 * tt;

    bf16x2 o;
    o[0] = f2bf(a0 * scale);
    o[1] = f2bf(a1 * scale);
    *(bf16x2*)&v2_bf[(size_t)row * 128 + lane * 2] = o;
}

// Epilogue: out = exp_map(v2 @ W^T + bias). Barrier-free tile loop: each wave
// owns a full 16-row tile; A-frags loaded straight from global (v2 row-major ==
// A-operand layout); W staged once in LDS; out-norm via in-quad shuffles.
__global__ __launch_bounds__(256)
void epilogue_kernel(const short* __restrict__ v2_bf,
                     const float* __restrict__ W,
                     const float* __restrict__ bias,
                     const float* __restrict__ c_ptr,
                     float* __restrict__ out,
                     int N, int tiles_per_wave) {
    __shared__ short Wl[128 * WPITCH];   // [o][k] bf16 (B-operand order)

    int tid = threadIdx.x;
    for (int i = tid; i < 4096; i += 256) {
        float4 w4 = ((const float4*)W)[i];
        int o = i >> 5;
        int k = (i & 31) * 4;
        bf16x4 w;
        w[0] = f2bf(w4.x); w[1] = f2bf(w4.y); w[2] = f2bf(w4.z); w[3] = f2bf(w4.w);
        *(bf16x4*)&Wl[o * WPITCH + k] = w;
    }
    __syncthreads();

    int wave = tid >> 6;
    int lane = tid & 63;
    int quad = lane >> 4;
    int l16  = lane & 15;
    float sc = sqrtf(c_ptr[0]);
    float bcol[8];
    #pragma unroll
    for (int ct = 0; ct < 8; ++ct) bcol[ct] = bias[ct * 16 + l16];

    int numTiles = (N + 15) / 16;
    int tile0 = (blockIdx.x * 4 + wave) * tiles_per_wave;

    for (int t = 0; t < tiles_per_wave; ++t) {
        int tile = tile0 + t;
        if (tile >= numTiles) break;
        int row0 = tile * 16;
        int rowA = min(row0 + l16, N - 1);   // clamp (dup rows harmless; stores guarded)

        bf16x8 af[4];
        #pragma unroll
        for (int k0 = 0; k0 < 4; ++k0)
            af[k0] = *(const bf16x8*)&v2_bf[(size_t)rowA * 128 + k0 * 32 + quad * 8];

        f32x4 acc[8];
        #pragma unroll
        for (int ct = 0; ct < 8; ++ct) {
            float b = bcol[ct];
            f32x4 a = {b, b, b, b};
            #pragma unroll
            for (int k0 = 0; k0 < 4; ++k0) {
                bf16x8 bf = *(const bf16x8*)&Wl[(ct * 16 + l16) * WPITCH + k0 * 32 + quad * 8];
                a = __builtin_amdgcn_mfma_f32_16x16x32_bf16(af[k0], bf, a, 0, 0, 0);
            }
            acc[ct] = a;
        }

        // per-row (quad*4+r) norm: sum over 8 col-tiles in-register + 16-lane shuffle
        #pragma unroll
        for (int r = 0; r < 4; ++r) {
            float ssum = 0.0f;
            #pragma unroll
            for (int ct = 0; ct < 8; ++ct) ssum += acc[ct][r] * acc[ct][r];
            ssum += __shfl_xor(ssum, 1);
            ssum += __shfl_xor(ssum, 2);
            ssum += __shfl_xor(ssum, 4);
            ssum += __shfl_xor(ssum, 8);
            float on  = sqrtf(ssum);
            float onc = fmaxf(on, EPSF);
            float g   = tanhf(sc * onc) / (sc * onc);
            int row = row0 + quad * 4 + r;
            if (row < N) {
                size_t base = (size_t)row * 128;
                #pragma unroll
                for (int ct = 0; ct < 8; ++ct)
                    out[base + ct * 16 + l16] = g * acc[ct][r];
            }
        }
    }
}

extern "C" void kernel_launch(void* const* d_in, const int* in_sizes, int n_in,
                              void* d_out, int out_size, void* d_ws, size_t ws_size,
                              hipStream_t stream) {
    const float* x     = (const float*)d_in[0];
    const int*   eidx  = (const int*)d_in[1];
    const float* c_ptr = (const float*)d_in[2];
    const float* W     = (const float*)d_in[4];
    const float* bias  = (const float*)d_in[5];
    float* out = (float*)d_out;

    int N = in_sizes[0] / 128;
    int E = in_sizes[1] / 2;

    short* v_bf        = (short*)d_ws;                     // N*128 bf16
    short* v2_bf       = v_bf + (size_t)N * 128;           // N*128 bf16
    int*   deg         = (int*)(v2_bf + (size_t)N * 128);  // N
    int*   offsets     = deg + N;                          // N
    int*   bucketCount = offsets + N;                      // NBUCK
    int*   cursor      = bucketCount + NBUCK;              // NBUCK
    int*   bucketed    = cursor + NBUCK;                   // E (packed)
    int*   sorted_src  = bucketed + E;                     // E

    hipMemsetAsync(bucketCount, 0, 2 * NBUCK * sizeof(int), stream);  // count+cursor

    {
        long long threads = (long long)N * 32;
        int blocks = (int)((threads + 255) / 256);
        hipLaunchKernelGGL(logmap_kernel, dim3(blocks), dim3(256), 0, stream,
                           x, c_ptr, v_bf, N);
    }
    hipLaunchKernelGGL(bucket_count_kernel, dim3(512), dim3(256), 0, stream,
                       eidx + E, bucketCount, E);
    {
        int blocks = (E + PB_CHUNK - 1) / PB_CHUNK;
        hipLaunchKernelGGL(bucket_scatter_kernel, dim3(blocks), dim3(256), 0, stream,
                           eidx, bucketCount, cursor, bucketed, E);
    }
    {
        int blocks = (N + 511) / 512;
        hipLaunchKernelGGL(csr_kernel, dim3(blocks), dim3(256), 0, stream,
                           bucketed, bucketCount, offsets, deg, sorted_src, N);
    }
    {
        int blocks = (N + 3) / 4;   // 4 waves/block, one wave per row
        hipLaunchKernelGGL(gather_kernel, dim3(blocks), dim3(256), 0, stream,
                           v_bf, sorted_src, offsets, deg, c_ptr, v2_bf, N);
    }
    {
        const int TPW = 4;
        int numTiles = (N + 15) / 16;
        int blocks = (numTiles + 4 * TPW - 1) / (4 * TPW);
        hipLaunchKernelGGL(epilogue_kernel, dim3(blocks), dim3(256), 0, stream,
                           v2_bf, W, bias, c_ptr, out, N, TPW);
    }
}